// Round 2
// baseline (1206.600 us; speedup 1.0000x reference)
//
#include <hip/hip_runtime.h>
#include <hip/hip_bf16.h>

static constexpr int NN = 50000;
static constexpr int NE = 1000000;

__device__ inline float bf2f_raw(unsigned short u) {
    return __uint_as_float(((unsigned int)u) << 16);
}

// ---------------- CSR build ----------------

__global__ void hist_kernel(const int* __restrict__ dst, int* __restrict__ deg) {
    int e = blockIdx.x * blockDim.x + threadIdx.x;
    if (e < NE) atomicAdd(&deg[dst[e]], 1);
}

__global__ __launch_bounds__(1024) void scan_kernel(const int* __restrict__ deg,
                                                    int* __restrict__ rowstart) {
    __shared__ int wave_sums[16];
    __shared__ int carry_s;
    int tid = threadIdx.x;
    int lane = tid & 63;
    int wave = tid >> 6;
    if (tid == 0) carry_s = 0;
    __syncthreads();
    for (int base = 0; base < NN; base += 1024) {
        int idx = base + tid;
        int v = (idx < NN) ? deg[idx] : 0;
        int x = v;
        #pragma unroll
        for (int off = 1; off < 64; off <<= 1) {
            int y = __shfl_up(x, off);
            if (lane >= off) x += y;
        }
        if (lane == 63) wave_sums[wave] = x;
        __syncthreads();
        if (wave == 0 && lane < 16) {
            int s = wave_sums[lane];
            #pragma unroll
            for (int off = 1; off < 16; off <<= 1) {
                int y = __shfl_up(s, off);
                if (lane >= off) s += y;
            }
            wave_sums[lane] = s;
        }
        __syncthreads();
        int wave_off = wave ? wave_sums[wave - 1] : 0;
        int chunk_total = wave_sums[15];
        int carry = carry_s;
        if (idx < NN) rowstart[idx] = carry + wave_off + x - v;  // exclusive scan
        __syncthreads();
        if (tid == 0) carry_s = carry + chunk_total;
        __syncthreads();
    }
    if (tid == 0) rowstart[NN] = carry_s;
}

__global__ void scatter_kernel(const int* __restrict__ src, const int* __restrict__ dst,
                               const int* __restrict__ rowstart, int* __restrict__ cursor,
                               int* __restrict__ csr) {
    int e = blockIdx.x * blockDim.x + threadIdx.x;
    if (e < NE) {
        int d = dst[e];
        int pos = atomicAdd(&cursor[d], 1);
        csr[rowstart[d] + pos] = src[e];
    }
}

// ---------------- weight split: Wtb = Wtop - Wbot, Wb = Wbot ----------------

template<int CIN, int COUT>
__global__ void prep_split_kernel(const float* __restrict__ W, float* __restrict__ Wtb,
                                  float* __restrict__ Wb) {
    int t = blockIdx.x * blockDim.x + threadIdx.x;
    if (t >= CIN * COUT) return;
    int k = t / COUT, c = t % COUT;
    float wt = W[k * COUT + c];
    float wb = W[(CIN + k) * COUT + c];
    Wtb[t] = wt - wb;
    Wb[t] = wb;
}

// ---------------- conv1 (K=3, elementwise) ----------------

__global__ void conv1_s_kernel(const float* __restrict__ x, const float* __restrict__ W1,
                               __hip_bfloat16* __restrict__ s) {
    int t = blockIdx.x * blockDim.x + threadIdx.x;
    int i = t >> 6, c = t & 63;
    if (i >= NN) return;
    float v = x[i * 3 + 0] * W1[3 * 64 + c] + x[i * 3 + 1] * W1[4 * 64 + c] +
              x[i * 3 + 2] * W1[5 * 64 + c];
    s[t] = __float2bfloat16(v);
}

__global__ void conv1_x_kernel(const float* __restrict__ x, const float* __restrict__ W1,
                               const float* __restrict__ b1,
                               const __hip_bfloat16* __restrict__ t1,
                               __hip_bfloat16* __restrict__ x1) {
    int t = blockIdx.x * blockDim.x + threadIdx.x;
    int i = t >> 6, c = t & 63;
    if (i >= NN) return;
    float a = x[i * 3 + 0] * (W1[0 * 64 + c] - W1[3 * 64 + c]) +
              x[i * 3 + 1] * (W1[1 * 64 + c] - W1[4 * 64 + c]) +
              x[i * 3 + 2] * (W1[2 * 64 + c] - W1[5 * 64 + c]) + b1[c];
    float v = a + __bfloat162float(t1[t]);
    x1[t] = __float2bfloat16(fmaxf(v, 0.f));
}

// ---------------- edge max gather: t[i][c] = max_{j in N(i)} s[j][c]  (empty -> -inf) ----------------

template<int C>
__global__ void edge_max_kernel(const __hip_bfloat16* __restrict__ s,
                                const int* __restrict__ rowstart, const int* __restrict__ csr,
                                __hip_bfloat16* __restrict__ t) {
    int gt = blockIdx.x * blockDim.x + threadIdx.x;
    int i = gt / C, c = gt % C;
    if (i >= NN) return;
    int e0 = rowstart[i], e1 = rowstart[i + 1];
    float acc = -INFINITY;
    for (int e = e0; e < e1; ++e) {
        int j = csr[e];
        acc = fmaxf(acc, __bfloat162float(s[(size_t)j * C + c]));
    }
    t[gt] = __float2bfloat16(acc);
}

// ---------------- GEMM: C_bf16 = epilogue(A_bf16[M,K] @ B_f32[K,N]) ----------------
// epilogue: + bias (if non-null), + T (if HAS_T, bf16), relu (if RELU)

template<bool HAS_T, bool RELU>
__global__ __launch_bounds__(256) void gemm_bf16a_kernel(
    const __hip_bfloat16* __restrict__ A, const float* __restrict__ B,
    const float* __restrict__ bias, const __hip_bfloat16* __restrict__ T,
    __hip_bfloat16* __restrict__ C, int M, int N, int K) {
    __shared__ __align__(16) float As[16][68];  // [k][m]
    __shared__ __align__(16) float Bs[16][64];  // [k][n]
    int tid = threadIdx.x;
    int mbase = blockIdx.y * 64, nbase = blockIdx.x * 64;
    int tx = tid & 15, ty = tid >> 4;
    int arow = tid & 63;
    int acol0 = (tid >> 6) * 4;
    int brow = tid >> 4;
    int bcol0 = (tid & 15) * 4;
    float acc[4][4] = {};
    for (int kb = 0; kb < K; kb += 16) {
        int gr = mbase + arow;
        ushort4 av = make_ushort4(0, 0, 0, 0);
        if (gr < M) av = *(const ushort4*)&A[(size_t)gr * K + kb + acol0];
        As[acol0 + 0][arow] = bf2f_raw(av.x);
        As[acol0 + 1][arow] = bf2f_raw(av.y);
        As[acol0 + 2][arow] = bf2f_raw(av.z);
        As[acol0 + 3][arow] = bf2f_raw(av.w);
        float4 bv = *(const float4*)&B[(size_t)(kb + brow) * N + nbase + bcol0];
        *(float4*)&Bs[brow][bcol0] = bv;
        __syncthreads();
        #pragma unroll
        for (int k = 0; k < 16; ++k) {
            float4 a4 = *(const float4*)&As[k][ty * 4];
            float4 b4 = *(const float4*)&Bs[k][tx * 4];
            float af[4] = {a4.x, a4.y, a4.z, a4.w};
            float bf[4] = {b4.x, b4.y, b4.z, b4.w};
            #pragma unroll
            for (int i = 0; i < 4; ++i)
                #pragma unroll
                for (int j = 0; j < 4; ++j)
                    acc[i][j] += af[i] * bf[j];
        }
        __syncthreads();
    }
    #pragma unroll
    for (int i = 0; i < 4; ++i) {
        int r = mbase + ty * 4 + i;
        if (r >= M) continue;
        #pragma unroll
        for (int j = 0; j < 4; ++j) {
            int cc = nbase + tx * 4 + j;
            float v = acc[i][j];
            if (bias) v += bias[cc];
            if (HAS_T) v += __bfloat162float(T[(size_t)r * N + cc]);
            if (RELU) v = fmaxf(v, 0.f);
            C[(size_t)r * N + cc] = __float2bfloat16(v);
        }
    }
}

// ---------------- final: out = x + h4 @ W5 + b5 (one wave per node) ----------------

__global__ void final_kernel(const __hip_bfloat16* __restrict__ h4, const float* __restrict__ W5,
                             const float* __restrict__ b5, const float* __restrict__ x,
                             float* __restrict__ out) {
    int gt = blockIdx.x * blockDim.x + threadIdx.x;
    int node = gt >> 6;
    int lane = gt & 63;
    if (node >= NN) return;
    ushort4 hv = ((const ushort4*)(h4 + (size_t)node * 256))[lane];
    float hj[4] = {bf2f_raw(hv.x), bf2f_raw(hv.y), bf2f_raw(hv.z), bf2f_raw(hv.w)};
    float acc0 = 0.f, acc1 = 0.f, acc2 = 0.f;
    #pragma unroll
    for (int j = 0; j < 4; ++j) {
        int k = lane * 4 + j;
        acc0 += hj[j] * W5[k * 3 + 0];
        acc1 += hj[j] * W5[k * 3 + 1];
        acc2 += hj[j] * W5[k * 3 + 2];
    }
    #pragma unroll
    for (int off = 32; off; off >>= 1) {
        acc0 += __shfl_down(acc0, off);
        acc1 += __shfl_down(acc1, off);
        acc2 += __shfl_down(acc2, off);
    }
    if (lane == 0) {
        out[node * 3 + 0] = x[node * 3 + 0] + acc0 + b5[0];
        out[node * 3 + 1] = x[node * 3 + 1] + acc1 + b5[1];
        out[node * 3 + 2] = x[node * 3 + 2] + acc2 + b5[2];
    }
}

// diagnostic fallback if workspace is too small: out = x (absmax will be ~4.4, not a crash)
__global__ void fallback_copy_kernel(const float* __restrict__ x, float* __restrict__ out) {
    int t = blockIdx.x * blockDim.x + threadIdx.x;
    if (t < NN * 3) out[t] = x[t];
}

// ---------------- launcher ----------------

extern "C" void kernel_launch(void* const* d_in, const int* in_sizes, int n_in,
                              void* d_out, int out_size, void* d_ws, size_t ws_size,
                              hipStream_t stream) {
    const float* x  = (const float*)d_in[0];
    const int*   ei = (const int*)d_in[1];
    const float* W1 = (const float*)d_in[2];
    const float* b1 = (const float*)d_in[3];
    const float* W2 = (const float*)d_in[4];
    const float* b2 = (const float*)d_in[5];
    const float* W3 = (const float*)d_in[6];
    const float* b3 = (const float*)d_in[7];
    const float* W4 = (const float*)d_in[8];
    const float* b4 = (const float*)d_in[9];
    const float* W5 = (const float*)d_in[10];
    const float* b5 = (const float*)d_in[11];
    float* out = (float*)d_out;

    char* p = (char*)d_ws;
    auto alloc = [&](size_t bytes) -> void* {
        void* r = (void*)p;
        p += (bytes + 255) & ~(size_t)255;
        return r;
    };
    int* deg      = (int*)alloc((size_t)NN * 4);
    int* rowstart = (int*)alloc((size_t)(NN + 1) * 4);
    int* cursor   = (int*)alloc((size_t)NN * 4);
    int* csr      = (int*)alloc((size_t)NE * 4);
    float* Wtb2 = (float*)alloc(64 * 128 * 4);
    float* Wb2  = (float*)alloc(64 * 128 * 4);
    float* Wtb3 = (float*)alloc(128 * 512 * 4);
    float* Wb3  = (float*)alloc(128 * 512 * 4);
    __hip_bfloat16* x1     = (__hip_bfloat16*)alloc((size_t)NN * 64 * 2);
    __hip_bfloat16* x2     = (__hip_bfloat16*)alloc((size_t)NN * 128 * 2);
    __hip_bfloat16* s_slab = (__hip_bfloat16*)alloc((size_t)NN * 512 * 2);  // s1/s2/s3, then x3
    __hip_bfloat16* t_slab = (__hip_bfloat16*)alloc((size_t)NN * 512 * 2);  // t1/t2/t3, then h4
    size_t need = (size_t)(p - (char*)d_ws);
    if (ws_size < need) {
        fallback_copy_kernel<<<(NN * 3 + 255) / 256, 256, 0, stream>>>(x, out);
        return;
    }
    __hip_bfloat16* x3 = s_slab;
    __hip_bfloat16* h4 = t_slab;

    const int* src = ei;        // edge_index[0]
    const int* dst = ei + NE;   // edge_index[1]

    // CSR by dst (graph static across all 3 convs)
    hipMemsetAsync(deg, 0, (size_t)NN * 4, stream);
    hipMemsetAsync(cursor, 0, (size_t)NN * 4, stream);
    hist_kernel<<<(NE + 255) / 256, 256, 0, stream>>>(dst, deg);
    scan_kernel<<<1, 1024, 0, stream>>>(deg, rowstart);
    scatter_kernel<<<(NE + 255) / 256, 256, 0, stream>>>(src, dst, rowstart, cursor, csr);

    // split weights
    prep_split_kernel<64, 128><<<32, 256, 0, stream>>>(W2, Wtb2, Wb2);
    prep_split_kernel<128, 512><<<256, 256, 0, stream>>>(W3, Wtb3, Wb3);

    // conv1: s1 = x@Wb1 ; t1 = edge-max(s1) ; x1 = relu(x@Wtb1 + b1 + t1)
    conv1_s_kernel<<<NN * 64 / 256, 256, 0, stream>>>(x, W1, s_slab);
    edge_max_kernel<64><<<NN * 64 / 256, 256, 0, stream>>>(s_slab, rowstart, csr, t_slab);
    conv1_x_kernel<<<NN * 64 / 256, 256, 0, stream>>>(x, W1, b1, t_slab, x1);

    // conv2
    gemm_bf16a_kernel<false, false><<<dim3(2, 782), 256, 0, stream>>>(
        x1, Wb2, nullptr, nullptr, s_slab, NN, 128, 64);
    edge_max_kernel<128><<<NN * 128 / 256, 256, 0, stream>>>(s_slab, rowstart, csr, t_slab);
    gemm_bf16a_kernel<true, true><<<dim3(2, 782), 256, 0, stream>>>(
        x1, Wtb2, b2, t_slab, x2, NN, 128, 64);

    // conv3
    gemm_bf16a_kernel<false, false><<<dim3(8, 782), 256, 0, stream>>>(
        x2, Wb3, nullptr, nullptr, s_slab, NN, 512, 128);
    edge_max_kernel<512><<<NN * 512 / 256, 256, 0, stream>>>(s_slab, rowstart, csr, t_slab);
    gemm_bf16a_kernel<true, true><<<dim3(8, 782), 256, 0, stream>>>(
        x2, Wtb3, b3, t_slab, x3, NN, 512, 128);

    // h4 = relu(x3 @ W4 + b4)
    gemm_bf16a_kernel<false, true><<<dim3(4, 782), 256, 0, stream>>>(
        x3, W4, b4, nullptr, h4, NN, 256, 512);

    // out = x + h4 @ W5 + b5
    final_kernel<<<NN / 4, 256, 0, stream>>>(h4, W5, b5, x, out);
}

// Round 3
// 700.947 us; speedup vs baseline: 1.7214x; 1.7214x over previous
//
#include <hip/hip_runtime.h>
#include <hip/hip_bf16.h>

static constexpr int NN = 50000;
static constexpr int NE = 1000000;

typedef short bf16x8 __attribute__((ext_vector_type(8)));
typedef float f32x4 __attribute__((ext_vector_type(4)));

__device__ inline float bf2f_raw(unsigned short u) {
    return __uint_as_float(((unsigned int)u) << 16);
}
__device__ inline unsigned short f2bf(float f) {
    unsigned int u = __float_as_uint(f);
    u += 0x7fffu + ((u >> 16) & 1u);
    return (unsigned short)(u >> 16);
}

// ---------------- CSR build ----------------

__global__ void hist_kernel(const int* __restrict__ dst, int* __restrict__ deg) {
    int e = blockIdx.x * blockDim.x + threadIdx.x;
    if (e < NE) atomicAdd(&deg[dst[e]], 1);
}

__global__ __launch_bounds__(1024) void scan_kernel(const int* __restrict__ deg,
                                                    int* __restrict__ rowstart) {
    __shared__ int wave_sums[16];
    __shared__ int carry_s;
    int tid = threadIdx.x;
    int lane = tid & 63;
    int wave = tid >> 6;
    if (tid == 0) carry_s = 0;
    __syncthreads();
    for (int base = 0; base < NN; base += 1024) {
        int idx = base + tid;
        int v = (idx < NN) ? deg[idx] : 0;
        int x = v;
        #pragma unroll
        for (int off = 1; off < 64; off <<= 1) {
            int y = __shfl_up(x, off);
            if (lane >= off) x += y;
        }
        if (lane == 63) wave_sums[wave] = x;
        __syncthreads();
        if (wave == 0 && lane < 16) {
            int s = wave_sums[lane];
            #pragma unroll
            for (int off = 1; off < 16; off <<= 1) {
                int y = __shfl_up(s, off);
                if (lane >= off) s += y;
            }
            wave_sums[lane] = s;
        }
        __syncthreads();
        int wave_off = wave ? wave_sums[wave - 1] : 0;
        int chunk_total = wave_sums[15];
        int carry = carry_s;
        if (idx < NN) rowstart[idx] = carry + wave_off + x - v;  // exclusive scan
        __syncthreads();
        if (tid == 0) carry_s = carry + chunk_total;
        __syncthreads();
    }
    if (tid == 0) rowstart[NN] = carry_s;
}

__global__ void scatter_kernel(const int* __restrict__ src, const int* __restrict__ dst,
                               const int* __restrict__ rowstart, int* __restrict__ cursor,
                               int* __restrict__ csr) {
    int e = blockIdx.x * blockDim.x + threadIdx.x;
    if (e < NE) {
        int d = dst[e];
        int pos = atomicAdd(&cursor[d], 1);
        csr[rowstart[d] + pos] = src[e];
    }
}

// ---------------- weight prep: bf16, transposed [COUT][CIN] ----------------

template<int CIN, int COUT>
__global__ void prep_split_t_kernel(const float* __restrict__ W,
                                    unsigned short* __restrict__ Wtbt,
                                    unsigned short* __restrict__ Wbt) {
    int t = blockIdx.x * blockDim.x + threadIdx.x;
    if (t >= CIN * COUT) return;
    int k = t / COUT, c = t % COUT;
    float wt = W[k * COUT + c];
    float wb = W[(CIN + k) * COUT + c];
    Wtbt[c * CIN + k] = f2bf(wt - wb);
    Wbt[c * CIN + k] = f2bf(wb);
}

template<int K, int N>
__global__ void prep_t_kernel(const float* __restrict__ W, unsigned short* __restrict__ Wt) {
    int t = blockIdx.x * blockDim.x + threadIdx.x;
    if (t >= K * N) return;
    int k = t / N, n = t % N;
    Wt[n * K + k] = f2bf(W[k * N + n]);
}

// ---------------- conv1 (K=3, elementwise) ----------------

__global__ void conv1_s_kernel(const float* __restrict__ x, const float* __restrict__ W1,
                               unsigned short* __restrict__ s) {
    int t = blockIdx.x * blockDim.x + threadIdx.x;
    int i = t >> 6, c = t & 63;
    if (i >= NN) return;
    float v = x[i * 3 + 0] * W1[3 * 64 + c] + x[i * 3 + 1] * W1[4 * 64 + c] +
              x[i * 3 + 2] * W1[5 * 64 + c];
    s[t] = f2bf(v);
}

__global__ void conv1_x_kernel(const float* __restrict__ x, const float* __restrict__ W1,
                               const float* __restrict__ b1,
                               const unsigned short* __restrict__ t1,
                               unsigned short* __restrict__ x1) {
    int t = blockIdx.x * blockDim.x + threadIdx.x;
    int i = t >> 6, c = t & 63;
    if (i >= NN) return;
    float a = x[i * 3 + 0] * (W1[0 * 64 + c] - W1[3 * 64 + c]) +
              x[i * 3 + 1] * (W1[1 * 64 + c] - W1[4 * 64 + c]) +
              x[i * 3 + 2] * (W1[2 * 64 + c] - W1[5 * 64 + c]) + b1[c];
    float v = a + bf2f_raw(t1[t]);
    x1[t] = f2bf(fmaxf(v, 0.f));
}

// ---------------- edge max, scalar (C=64): t[i][c] = max_j s[j][c] ----------------

template<int C>
__global__ void edge_max_kernel(const unsigned short* __restrict__ s,
                                const int* __restrict__ rowstart, const int* __restrict__ csr,
                                unsigned short* __restrict__ t) {
    int gt = blockIdx.x * blockDim.x + threadIdx.x;
    int i = gt / C, c = gt % C;
    if (i >= NN) return;
    int e0 = rowstart[i], e1 = rowstart[i + 1];
    float acc = -INFINITY;
    for (int e = e0; e < e1; ++e) {
        int j = csr[e];
        acc = fmaxf(acc, bf2f_raw(s[(size_t)j * C + c]));
    }
    t[gt] = f2bf(acc);
}

// ---------------- edge max, vectorized: one wave per node, VEC channels/lane ----------------

template<int C, int VEC>
__global__ __launch_bounds__(256) void edge_max_vec_kernel(
    const unsigned short* __restrict__ s, const int* __restrict__ rowstart,
    const int* __restrict__ csr, unsigned short* __restrict__ t) {
    int wid = (blockIdx.x * 256 + threadIdx.x) >> 6;
    int lane = threadIdx.x & 63;
    if (wid >= NN) return;
    int e0 = __builtin_amdgcn_readfirstlane(rowstart[wid]);
    int e1 = __builtin_amdgcn_readfirstlane(rowstart[wid + 1]);
    float acc[VEC];
    #pragma unroll
    for (int v = 0; v < VEC; ++v) acc[v] = -INFINITY;
    const unsigned short* sl = s + (size_t)lane * VEC;
    int nedge = e1 - e0;
    for (int base = 0; base < nedge; base += 64) {
        int rem = nedge - base;
        int myj = (lane < rem) ? csr[e0 + base + lane] : 0;
        int cnt = rem < 64 ? rem : 64;
        int q = 0;
        for (; q + 1 < cnt; q += 2) {
            int j0 = __shfl(myj, q);
            int j1 = __shfl(myj, q + 1);
            if constexpr (VEC == 8) {
                uint4 v0 = *(const uint4*)(sl + (size_t)j0 * C);
                uint4 v1 = *(const uint4*)(sl + (size_t)j1 * C);
                acc[0] = fmaxf(acc[0], bf2f_raw((unsigned short)(v0.x & 0xffff)));
                acc[1] = fmaxf(acc[1], bf2f_raw((unsigned short)(v0.x >> 16)));
                acc[2] = fmaxf(acc[2], bf2f_raw((unsigned short)(v0.y & 0xffff)));
                acc[3] = fmaxf(acc[3], bf2f_raw((unsigned short)(v0.y >> 16)));
                acc[4] = fmaxf(acc[4], bf2f_raw((unsigned short)(v0.z & 0xffff)));
                acc[5] = fmaxf(acc[5], bf2f_raw((unsigned short)(v0.z >> 16)));
                acc[6] = fmaxf(acc[6], bf2f_raw((unsigned short)(v0.w & 0xffff)));
                acc[7] = fmaxf(acc[7], bf2f_raw((unsigned short)(v0.w >> 16)));
                acc[0] = fmaxf(acc[0], bf2f_raw((unsigned short)(v1.x & 0xffff)));
                acc[1] = fmaxf(acc[1], bf2f_raw((unsigned short)(v1.x >> 16)));
                acc[2] = fmaxf(acc[2], bf2f_raw((unsigned short)(v1.y & 0xffff)));
                acc[3] = fmaxf(acc[3], bf2f_raw((unsigned short)(v1.y >> 16)));
                acc[4] = fmaxf(acc[4], bf2f_raw((unsigned short)(v1.z & 0xffff)));
                acc[5] = fmaxf(acc[5], bf2f_raw((unsigned short)(v1.z >> 16)));
                acc[6] = fmaxf(acc[6], bf2f_raw((unsigned short)(v1.w & 0xffff)));
                acc[7] = fmaxf(acc[7], bf2f_raw((unsigned short)(v1.w >> 16)));
            } else {
                unsigned int v0 = *(const unsigned int*)(sl + (size_t)j0 * C);
                unsigned int v1 = *(const unsigned int*)(sl + (size_t)j1 * C);
                acc[0] = fmaxf(acc[0], bf2f_raw((unsigned short)(v0 & 0xffff)));
                acc[1] = fmaxf(acc[1], bf2f_raw((unsigned short)(v0 >> 16)));
                acc[0] = fmaxf(acc[0], bf2f_raw((unsigned short)(v1 & 0xffff)));
                acc[1] = fmaxf(acc[1], bf2f_raw((unsigned short)(v1 >> 16)));
            }
        }
        if (q < cnt) {
            int j0 = __shfl(myj, q);
            if constexpr (VEC == 8) {
                uint4 v0 = *(const uint4*)(sl + (size_t)j0 * C);
                acc[0] = fmaxf(acc[0], bf2f_raw((unsigned short)(v0.x & 0xffff)));
                acc[1] = fmaxf(acc[1], bf2f_raw((unsigned short)(v0.x >> 16)));
                acc[2] = fmaxf(acc[2], bf2f_raw((unsigned short)(v0.y & 0xffff)));
                acc[3] = fmaxf(acc[3], bf2f_raw((unsigned short)(v0.y >> 16)));
                acc[4] = fmaxf(acc[4], bf2f_raw((unsigned short)(v0.z & 0xffff)));
                acc[5] = fmaxf(acc[5], bf2f_raw((unsigned short)(v0.z >> 16)));
                acc[6] = fmaxf(acc[6], bf2f_raw((unsigned short)(v0.w & 0xffff)));
                acc[7] = fmaxf(acc[7], bf2f_raw((unsigned short)(v0.w >> 16)));
            } else {
                unsigned int v0 = *(const unsigned int*)(sl + (size_t)j0 * C);
                acc[0] = fmaxf(acc[0], bf2f_raw((unsigned short)(v0 & 0xffff)));
                acc[1] = fmaxf(acc[1], bf2f_raw((unsigned short)(v0 >> 16)));
            }
        }
    }
    unsigned short* tp = t + (size_t)wid * C + lane * VEC;
    if constexpr (VEC == 8) {
        uint4 o;
        o.x = (unsigned int)f2bf(acc[0]) | ((unsigned int)f2bf(acc[1]) << 16);
        o.y = (unsigned int)f2bf(acc[2]) | ((unsigned int)f2bf(acc[3]) << 16);
        o.z = (unsigned int)f2bf(acc[4]) | ((unsigned int)f2bf(acc[5]) << 16);
        o.w = (unsigned int)f2bf(acc[6]) | ((unsigned int)f2bf(acc[7]) << 16);
        *(uint4*)tp = o;
    } else {
        *(unsigned int*)tp = (unsigned int)f2bf(acc[0]) | ((unsigned int)f2bf(acc[1]) << 16);
    }
}

// ---------------- MFMA GEMM: C_bf16 = epi(A_bf16[M,K] @ B, Bt = B^T bf16 [N][K]) ----------------
// 128x128 block tile, 4 waves, each wave 64x64 via 4x4 mfma_f32_16x16x32_bf16.
// Requires K % 32 == 0, N % 128 == 0 (or exact multiple of tiles launched).

template<bool HAS_T, bool RELU>
__global__ __launch_bounds__(256) void mfma_gemm_kernel(
    const unsigned short* __restrict__ A, const unsigned short* __restrict__ Bt,
    const float* __restrict__ bias, const unsigned short* __restrict__ T,
    unsigned short* __restrict__ C, int M, int N, int K) {
    __shared__ __align__(16) unsigned short Asl[128 * 40];  // [m][k], stride 40 (pad)
    __shared__ __align__(16) unsigned short Bsl[128 * 40];  // [n][k], stride 40
    int tid = threadIdx.x;
    int mbase = blockIdx.y * 128, nbase = blockIdx.x * 128;
    int wave = tid >> 6, lane = tid & 63;
    int wm = (wave >> 1) * 64, wn = (wave & 1) * 64;
    int quad = lane >> 4, l16 = lane & 15;
    f32x4 acc[4][4] = {};
    for (int kb = 0; kb < K; kb += 32) {
        #pragma unroll
        for (int h = 0; h < 2; ++h) {
            int c = tid + h * 256;           // 512 chunks of 16B
            int r = c >> 2, kk = (c & 3) * 8;
            uint4 va = make_uint4(0u, 0u, 0u, 0u);
            int gr = mbase + r;
            if (gr < M) va = *(const uint4*)&A[(size_t)gr * K + kb + kk];
            *(uint4*)&Asl[r * 40 + kk] = va;
            uint4 vb = *(const uint4*)&Bt[(size_t)(nbase + r) * K + kb + kk];
            *(uint4*)&Bsl[r * 40 + kk] = vb;
        }
        __syncthreads();
        bf16x8 af[4], bfr[4];
        #pragma unroll
        for (int tt = 0; tt < 4; ++tt) {
            af[tt]  = *(const bf16x8*)&Asl[(wm + tt * 16 + l16) * 40 + quad * 8];
            bfr[tt] = *(const bf16x8*)&Bsl[(wn + tt * 16 + l16) * 40 + quad * 8];
        }
        #pragma unroll
        for (int mt = 0; mt < 4; ++mt)
            #pragma unroll
            for (int nt = 0; nt < 4; ++nt)
                acc[mt][nt] = __builtin_amdgcn_mfma_f32_16x16x32_bf16(
                    af[mt], bfr[nt], acc[mt][nt], 0, 0, 0);
        __syncthreads();
    }
    #pragma unroll
    for (int mt = 0; mt < 4; ++mt) {
        #pragma unroll
        for (int r = 0; r < 4; ++r) {
            int row = mbase + wm + mt * 16 + quad * 4 + r;
            if (row >= M) continue;
            #pragma unroll
            for (int nt = 0; nt < 4; ++nt) {
                int col = nbase + wn + nt * 16 + l16;
                float v = acc[mt][nt][r];
                if (bias) v += bias[col];
                if (HAS_T) v += bf2f_raw(T[(size_t)row * N + col]);
                if (RELU) v = fmaxf(v, 0.f);
                C[(size_t)row * N + col] = f2bf(v);
            }
        }
    }
}

// ---------------- final: out = x + h4 @ W5 + b5 (one wave per node) ----------------

__global__ void final_kernel(const unsigned short* __restrict__ h4,
                             const float* __restrict__ W5, const float* __restrict__ b5,
                             const float* __restrict__ x, float* __restrict__ out) {
    int gt = blockIdx.x * blockDim.x + threadIdx.x;
    int node = gt >> 6;
    int lane = gt & 63;
    if (node >= NN) return;
    ushort4 hv = ((const ushort4*)(h4 + (size_t)node * 256))[lane];
    float hj[4] = {bf2f_raw(hv.x), bf2f_raw(hv.y), bf2f_raw(hv.z), bf2f_raw(hv.w)};
    float acc0 = 0.f, acc1 = 0.f, acc2 = 0.f;
    #pragma unroll
    for (int j = 0; j < 4; ++j) {
        int k = lane * 4 + j;
        acc0 += hj[j] * W5[k * 3 + 0];
        acc1 += hj[j] * W5[k * 3 + 1];
        acc2 += hj[j] * W5[k * 3 + 2];
    }
    #pragma unroll
    for (int off = 32; off; off >>= 1) {
        acc0 += __shfl_down(acc0, off);
        acc1 += __shfl_down(acc1, off);
        acc2 += __shfl_down(acc2, off);
    }
    if (lane == 0) {
        out[node * 3 + 0] = x[node * 3 + 0] + acc0 + b5[0];
        out[node * 3 + 1] = x[node * 3 + 1] + acc1 + b5[1];
        out[node * 3 + 2] = x[node * 3 + 2] + acc2 + b5[2];
    }
}

__global__ void fallback_copy_kernel(const float* __restrict__ x, float* __restrict__ out) {
    int t = blockIdx.x * blockDim.x + threadIdx.x;
    if (t < NN * 3) out[t] = x[t];
}

// ---------------- launcher ----------------

extern "C" void kernel_launch(void* const* d_in, const int* in_sizes, int n_in,
                              void* d_out, int out_size, void* d_ws, size_t ws_size,
                              hipStream_t stream) {
    const float* x  = (const float*)d_in[0];
    const int*   ei = (const int*)d_in[1];
    const float* W1 = (const float*)d_in[2];
    const float* b1 = (const float*)d_in[3];
    const float* W2 = (const float*)d_in[4];
    const float* b2 = (const float*)d_in[5];
    const float* W3 = (const float*)d_in[6];
    const float* b3 = (const float*)d_in[7];
    const float* W4 = (const float*)d_in[8];
    const float* b4 = (const float*)d_in[9];
    const float* W5 = (const float*)d_in[10];
    const float* b5 = (const float*)d_in[11];
    float* out = (float*)d_out;

    char* p = (char*)d_ws;
    auto alloc = [&](size_t bytes) -> void* {
        void* r = (void*)p;
        p += (bytes + 255) & ~(size_t)255;
        return r;
    };
    int* deg      = (int*)alloc((size_t)NN * 4);
    int* rowstart = (int*)alloc((size_t)(NN + 1) * 4);
    int* cursor   = (int*)alloc((size_t)NN * 4);
    int* csr      = (int*)alloc((size_t)NE * 4);
    unsigned short* Wtb2t = (unsigned short*)alloc(128 * 64 * 2);
    unsigned short* Wb2t  = (unsigned short*)alloc(128 * 64 * 2);
    unsigned short* Wtb3t = (unsigned short*)alloc(512 * 128 * 2);
    unsigned short* Wb3t  = (unsigned short*)alloc(512 * 128 * 2);
    unsigned short* W4t   = (unsigned short*)alloc(256 * 512 * 2);
    unsigned short* x1     = (unsigned short*)alloc((size_t)NN * 64 * 2);
    unsigned short* x2     = (unsigned short*)alloc((size_t)NN * 128 * 2);
    unsigned short* s_slab = (unsigned short*)alloc((size_t)NN * 512 * 2);  // s1/s2/s3, then x3
    unsigned short* t_slab = (unsigned short*)alloc((size_t)NN * 512 * 2);  // t1/t2/t3, then h4
    size_t need = (size_t)(p - (char*)d_ws);
    if (ws_size < need) {
        fallback_copy_kernel<<<(NN * 3 + 255) / 256, 256, 0, stream>>>(x, out);
        return;
    }
    unsigned short* x3 = s_slab;
    unsigned short* h4 = t_slab;

    const int* src = ei;        // edge_index[0]
    const int* dst = ei + NE;   // edge_index[1]

    // CSR by dst (graph static across all 3 convs)
    hipMemsetAsync(deg, 0, (size_t)NN * 4, stream);
    hipMemsetAsync(cursor, 0, (size_t)NN * 4, stream);
    hist_kernel<<<(NE + 255) / 256, 256, 0, stream>>>(dst, deg);
    scan_kernel<<<1, 1024, 0, stream>>>(deg, rowstart);
    scatter_kernel<<<(NE + 255) / 256, 256, 0, stream>>>(src, dst, rowstart, cursor, csr);

    // bf16 transposed weights
    prep_split_t_kernel<64, 128><<<32, 256, 0, stream>>>(W2, Wtb2t, Wb2t);
    prep_split_t_kernel<128, 512><<<256, 256, 0, stream>>>(W3, Wtb3t, Wb3t);
    prep_t_kernel<512, 256><<<512, 256, 0, stream>>>(W4, W4t);

    // conv1: s1 = x@Wb1 ; t1 = edge-max(s1) ; x1 = relu(x@Wtb1 + b1 + t1)
    conv1_s_kernel<<<NN * 64 / 256, 256, 0, stream>>>(x, W1, s_slab);
    edge_max_kernel<64><<<NN * 64 / 256, 256, 0, stream>>>(s_slab, rowstart, csr, t_slab);
    conv1_x_kernel<<<NN * 64 / 256, 256, 0, stream>>>(x, W1, b1, t_slab, x1);

    // conv2 (M=NN, N=128, K=64)
    mfma_gemm_kernel<false, false><<<dim3(1, 391), 256, 0, stream>>>(
        x1, Wb2t, nullptr, nullptr, s_slab, NN, 128, 64);
    edge_max_vec_kernel<128, 2><<<12500, 256, 0, stream>>>(s_slab, rowstart, csr, t_slab);
    mfma_gemm_kernel<true, true><<<dim3(1, 391), 256, 0, stream>>>(
        x1, Wtb2t, b2, t_slab, x2, NN, 128, 64);

    // conv3 (M=NN, N=512, K=128)
    mfma_gemm_kernel<false, false><<<dim3(4, 391), 256, 0, stream>>>(
        x2, Wb3t, nullptr, nullptr, s_slab, NN, 512, 128);
    edge_max_vec_kernel<512, 8><<<12500, 256, 0, stream>>>(s_slab, rowstart, csr, t_slab);
    mfma_gemm_kernel<true, true><<<dim3(4, 391), 256, 0, stream>>>(
        x2, Wtb3t, b3, t_slab, x3, NN, 512, 128);

    // h4 = relu(x3 @ W4 + b4)  (M=NN, N=256, K=512)
    mfma_gemm_kernel<false, true><<<dim3(2, 391), 256, 0, stream>>>(
        x3, W4t, b4, nullptr, h4, NN, 256, 512);

    // out = x + h4 @ W5 + b5
    final_kernel<<<NN / 4, 256, 0, stream>>>(h4, W5, b5, x, out);
}

// Round 4
// 630.209 us; speedup vs baseline: 1.9146x; 1.1122x over previous
//
#include <hip/hip_runtime.h>

static constexpr int NN = 50000;
static constexpr int NE = 1000000;

typedef short bf16x8 __attribute__((ext_vector_type(8)));
typedef float f32x4 __attribute__((ext_vector_type(4)));

__device__ inline float bf2f_raw(unsigned short u) {
    return __uint_as_float(((unsigned int)u) << 16);
}
__device__ inline unsigned short f2bf(float f) {
    unsigned int u = __float_as_uint(f);
    u += 0x7fffu + ((u >> 16) & 1u);
    return (unsigned short)(u >> 16);
}
__device__ inline void fmax2(float& a0, float& a1, unsigned int v) {
    a0 = fmaxf(a0, bf2f_raw((unsigned short)(v & 0xffffu)));
    a1 = fmaxf(a1, bf2f_raw((unsigned short)(v >> 16)));
}
__device__ inline unsigned int pack2(float f0, float f1) {
    return (unsigned int)f2bf(f0) | ((unsigned int)f2bf(f1) << 16);
}
// x_out pair = relu(a_pair + t), a packed bf16x2
__device__ inline unsigned int addrelu2(unsigned int a, float t0, float t1) {
    float f0 = fmaxf(bf2f_raw((unsigned short)(a & 0xffffu)) + t0, 0.f);
    float f1 = fmaxf(bf2f_raw((unsigned short)(a >> 16)) + t1, 0.f);
    return pack2(f0, f1);
}

// ---------------- CSR build ----------------

__global__ void hist_kernel(const int* __restrict__ dst, int* __restrict__ deg) {
    int e = blockIdx.x * blockDim.x + threadIdx.x;
    if (e < NE) atomicAdd(&deg[dst[e]], 1);
}

__global__ __launch_bounds__(1024) void scan_kernel(const int* __restrict__ deg,
                                                    int* __restrict__ rowstart) {
    __shared__ int wave_sums[16];
    __shared__ int carry_s;
    int tid = threadIdx.x;
    int lane = tid & 63;
    int wave = tid >> 6;
    if (tid == 0) carry_s = 0;
    __syncthreads();
    for (int base = 0; base < NN; base += 1024) {
        int idx = base + tid;
        int v = (idx < NN) ? deg[idx] : 0;
        int x = v;
        #pragma unroll
        for (int off = 1; off < 64; off <<= 1) {
            int y = __shfl_up(x, off);
            if (lane >= off) x += y;
        }
        if (lane == 63) wave_sums[wave] = x;
        __syncthreads();
        if (wave == 0 && lane < 16) {
            int s = wave_sums[lane];
            #pragma unroll
            for (int off = 1; off < 16; off <<= 1) {
                int y = __shfl_up(s, off);
                if (lane >= off) s += y;
            }
            wave_sums[lane] = s;
        }
        __syncthreads();
        int wave_off = wave ? wave_sums[wave - 1] : 0;
        int chunk_total = wave_sums[15];
        int carry = carry_s;
        if (idx < NN) rowstart[idx] = carry + wave_off + x - v;  // exclusive scan
        __syncthreads();
        if (tid == 0) carry_s = carry + chunk_total;
        __syncthreads();
    }
    if (tid == 0) rowstart[NN] = carry_s;
}

__global__ void scatter_kernel(const int* __restrict__ src, const int* __restrict__ dst,
                               const int* __restrict__ rowstart, int* __restrict__ cursor,
                               int* __restrict__ csr) {
    int e = blockIdx.x * blockDim.x + threadIdx.x;
    if (e < NE) {
        int d = dst[e];
        int pos = atomicAdd(&cursor[d], 1);
        csr[rowstart[d] + pos] = src[e];
    }
}

// ---------------- weight prep: bf16, transposed [COUT][CIN] ----------------

template<int CIN, int COUT>
__global__ void prep_split_t_kernel(const float* __restrict__ W,
                                    unsigned short* __restrict__ Wtbt,
                                    unsigned short* __restrict__ Wbt) {
    int t = blockIdx.x * blockDim.x + threadIdx.x;
    if (t >= CIN * COUT) return;
    int k = t / COUT, c = t % COUT;
    float wt = W[k * COUT + c];
    float wb = W[(CIN + k) * COUT + c];
    Wtbt[c * CIN + k] = f2bf(wt - wb);
    Wbt[c * CIN + k] = f2bf(wb);
}

template<int K, int N>
__global__ void prep_t_kernel(const float* __restrict__ W, unsigned short* __restrict__ Wt) {
    int t = blockIdx.x * blockDim.x + threadIdx.x;
    if (t >= K * N) return;
    int k = t / N, n = t % N;
    Wt[n * K + k] = f2bf(W[k * N + n]);
}

// ---------------- conv1 s = x @ Wb1 (K=3, elementwise) ----------------

__global__ void conv1_s_kernel(const float* __restrict__ x, const float* __restrict__ W1,
                               unsigned short* __restrict__ s) {
    int t = blockIdx.x * blockDim.x + threadIdx.x;
    int i = t >> 6, c = t & 63;
    if (i >= NN) return;
    float v = x[i * 3 + 0] * W1[3 * 64 + c] + x[i * 3 + 1] * W1[4 * 64 + c] +
              x[i * 3 + 2] * W1[5 * 64 + c];
    s[t] = f2bf(v);
}

// ---------------- conv1 fused edge-max + epilogue (C=64) ----------------
// one wave per node; lane-halves process alternate edges; a computed inline from x.

__global__ __launch_bounds__(256) void edge_fused_conv1_kernel(
    const unsigned short* __restrict__ s1, const int* __restrict__ rowstart,
    const int* __restrict__ csr, const float* __restrict__ x,
    const float* __restrict__ W1, const float* __restrict__ b1,
    unsigned short* __restrict__ x1) {
    int wid = (blockIdx.x * 256 + threadIdx.x) >> 6;
    int lane = threadIdx.x & 63;
    if (wid >= NN) return;
    int e0 = __builtin_amdgcn_readfirstlane(rowstart[wid]);
    int e1 = __builtin_amdgcn_readfirstlane(rowstart[wid + 1]);
    int h = lane >> 5, c0 = (lane & 31) * 2;
    float t0 = -INFINITY, t1 = -INFINITY;
    const unsigned short* sb = s1 + c0;
    int nedge = e1 - e0;
    for (int base = 0; base < nedge; base += 64) {
        int rem = nedge - base;
        int myj = csr[(lane < rem) ? (e0 + base + lane) : e0];
        int cnt = rem < 64 ? rem : 64;
        int cp = (cnt + 7) & ~7;
        for (int q = 0; q < cp; q += 8) {
            int j0 = __shfl(myj, q + 0 + h);
            int j1 = __shfl(myj, q + 2 + h);
            int j2 = __shfl(myj, q + 4 + h);
            int j3 = __shfl(myj, q + 6 + h);
            unsigned int v0 = *(const unsigned int*)(sb + (size_t)j0 * 64);
            unsigned int v1 = *(const unsigned int*)(sb + (size_t)j1 * 64);
            unsigned int v2 = *(const unsigned int*)(sb + (size_t)j2 * 64);
            unsigned int v3 = *(const unsigned int*)(sb + (size_t)j3 * 64);
            fmax2(t0, t1, v0);
            fmax2(t0, t1, v1);
            fmax2(t0, t1, v2);
            fmax2(t0, t1, v3);
        }
    }
    t0 = fmaxf(t0, __shfl_xor(t0, 32));
    t1 = fmaxf(t1, __shfl_xor(t1, 32));
    if (h == 0) {
        float x0 = x[wid * 3 + 0], xv1 = x[wid * 3 + 1], xv2 = x[wid * 3 + 2];
        int c1 = c0 + 1;
        float a0 = x0 * (W1[c0] - W1[192 + c0]) + xv1 * (W1[64 + c0] - W1[256 + c0]) +
                   xv2 * (W1[128 + c0] - W1[320 + c0]) + b1[c0];
        float a1 = x0 * (W1[c1] - W1[192 + c1]) + xv1 * (W1[64 + c1] - W1[256 + c1]) +
                   xv2 * (W1[128 + c1] - W1[320 + c1]) + b1[c1];
        *(unsigned int*)(x1 + (size_t)wid * 64 + c0) =
            pack2(fmaxf(a0 + t0, 0.f), fmaxf(a1 + t1, 0.f));
    }
}

// ---------------- fused edge-max + epilogue, C=128 (as rows [a(128)|s(128)]) ----------------

__global__ __launch_bounds__(256) void edge_fused128_kernel(
    const unsigned short* __restrict__ as, const int* __restrict__ rowstart,
    const int* __restrict__ csr, unsigned short* __restrict__ xout) {
    int wid = (blockIdx.x * 256 + threadIdx.x) >> 6;
    int lane = threadIdx.x & 63;
    if (wid >= NN) return;
    int e0 = __builtin_amdgcn_readfirstlane(rowstart[wid]);
    int e1 = __builtin_amdgcn_readfirstlane(rowstart[wid + 1]);
    float t0 = -INFINITY, t1 = -INFINITY;
    const unsigned short* sb = as + 128 + (size_t)lane * 2;
    int nedge = e1 - e0;
    for (int base = 0; base < nedge; base += 64) {
        int rem = nedge - base;
        int myj = csr[(lane < rem) ? (e0 + base + lane) : e0];
        int cnt = rem < 64 ? rem : 64;
        int cp = (cnt + 3) & ~3;
        for (int q = 0; q < cp; q += 4) {
            int j0 = __shfl(myj, q + 0), j1 = __shfl(myj, q + 1);
            int j2 = __shfl(myj, q + 2), j3 = __shfl(myj, q + 3);
            unsigned int v0 = *(const unsigned int*)(sb + (size_t)j0 * 256);
            unsigned int v1 = *(const unsigned int*)(sb + (size_t)j1 * 256);
            unsigned int v2 = *(const unsigned int*)(sb + (size_t)j2 * 256);
            unsigned int v3 = *(const unsigned int*)(sb + (size_t)j3 * 256);
            fmax2(t0, t1, v0);
            fmax2(t0, t1, v1);
            fmax2(t0, t1, v2);
            fmax2(t0, t1, v3);
        }
    }
    unsigned int av = *(const unsigned int*)(as + (size_t)wid * 256 + lane * 2);
    *(unsigned int*)(xout + (size_t)wid * 128 + lane * 2) = addrelu2(av, t0, t1);
}

// ---------------- fused edge-max + epilogue, C=512 (as rows [a(512)|s(512)]) ----------------

__global__ __launch_bounds__(256) void edge_fused512_kernel(
    const unsigned short* __restrict__ as, const int* __restrict__ rowstart,
    const int* __restrict__ csr, unsigned short* __restrict__ xout) {
    int wid = (blockIdx.x * 256 + threadIdx.x) >> 6;
    int lane = threadIdx.x & 63;
    if (wid >= NN) return;
    int e0 = __builtin_amdgcn_readfirstlane(rowstart[wid]);
    int e1 = __builtin_amdgcn_readfirstlane(rowstart[wid + 1]);
    float acc[8];
    #pragma unroll
    for (int v = 0; v < 8; ++v) acc[v] = -INFINITY;
    const unsigned short* sb = as + 512 + (size_t)lane * 8;
    int nedge = e1 - e0;
    for (int base = 0; base < nedge; base += 64) {
        int rem = nedge - base;
        int myj = csr[(lane < rem) ? (e0 + base + lane) : e0];
        int cnt = rem < 64 ? rem : 64;
        int cp = (cnt + 3) & ~3;
        for (int q = 0; q < cp; q += 4) {
            int j0 = __shfl(myj, q + 0), j1 = __shfl(myj, q + 1);
            int j2 = __shfl(myj, q + 2), j3 = __shfl(myj, q + 3);
            uint4 v0 = *(const uint4*)(sb + (size_t)j0 * 1024);
            uint4 v1 = *(const uint4*)(sb + (size_t)j1 * 1024);
            uint4 v2 = *(const uint4*)(sb + (size_t)j2 * 1024);
            uint4 v3 = *(const uint4*)(sb + (size_t)j3 * 1024);
            fmax2(acc[0], acc[1], v0.x); fmax2(acc[2], acc[3], v0.y);
            fmax2(acc[4], acc[5], v0.z); fmax2(acc[6], acc[7], v0.w);
            fmax2(acc[0], acc[1], v1.x); fmax2(acc[2], acc[3], v1.y);
            fmax2(acc[4], acc[5], v1.z); fmax2(acc[6], acc[7], v1.w);
            fmax2(acc[0], acc[1], v2.x); fmax2(acc[2], acc[3], v2.y);
            fmax2(acc[4], acc[5], v2.z); fmax2(acc[6], acc[7], v2.w);
            fmax2(acc[0], acc[1], v3.x); fmax2(acc[2], acc[3], v3.y);
            fmax2(acc[4], acc[5], v3.z); fmax2(acc[6], acc[7], v3.w);
        }
    }
    uint4 av = *(const uint4*)(as + (size_t)wid * 1024 + lane * 8);
    uint4 o;
    o.x = addrelu2(av.x, acc[0], acc[1]);
    o.y = addrelu2(av.y, acc[2], acc[3]);
    o.z = addrelu2(av.z, acc[4], acc[5]);
    o.w = addrelu2(av.w, acc[6], acc[7]);
    *(uint4*)(xout + (size_t)wid * 512 + lane * 8) = o;
}

// ---------------- MFMA GEMM: C_bf16 = epi(A_bf16[M,K] @ B), Bt = B^T bf16 [N][K] ----------------
// 128x128 block tile, 4 waves, each 64x64 via 4x4 mfma_f32_16x16x32_bf16.
// bias applied to cols < bias_n.

template<bool RELU>
__global__ __launch_bounds__(256) void mfma_gemm_kernel(
    const unsigned short* __restrict__ A, const unsigned short* __restrict__ Bt,
    const float* __restrict__ bias, int bias_n,
    unsigned short* __restrict__ C, int M, int N, int K) {
    __shared__ __align__(16) unsigned short Asl[128 * 40];  // [m][k], stride 40 (pad)
    __shared__ __align__(16) unsigned short Bsl[128 * 40];  // [n][k], stride 40
    int tid = threadIdx.x;
    int mbase = blockIdx.y * 128, nbase = blockIdx.x * 128;
    int wave = tid >> 6, lane = tid & 63;
    int wm = (wave >> 1) * 64, wn = (wave & 1) * 64;
    int quad = lane >> 4, l16 = lane & 15;
    f32x4 acc[4][4] = {};
    for (int kb = 0; kb < K; kb += 32) {
        #pragma unroll
        for (int h = 0; h < 2; ++h) {
            int c = tid + h * 256;           // 512 chunks of 16B
            int r = c >> 2, kk = (c & 3) * 8;
            uint4 va = make_uint4(0u, 0u, 0u, 0u);
            int gr = mbase + r;
            if (gr < M) va = *(const uint4*)&A[(size_t)gr * K + kb + kk];
            *(uint4*)&Asl[r * 40 + kk] = va;
            uint4 vb = *(const uint4*)&Bt[(size_t)(nbase + r) * K + kb + kk];
            *(uint4*)&Bsl[r * 40 + kk] = vb;
        }
        __syncthreads();
        bf16x8 af[4], bfr[4];
        #pragma unroll
        for (int tt = 0; tt < 4; ++tt) {
            af[tt]  = *(const bf16x8*)&Asl[(wm + tt * 16 + l16) * 40 + quad * 8];
            bfr[tt] = *(const bf16x8*)&Bsl[(wn + tt * 16 + l16) * 40 + quad * 8];
        }
        #pragma unroll
        for (int mt = 0; mt < 4; ++mt)
            #pragma unroll
            for (int nt = 0; nt < 4; ++nt)
                acc[mt][nt] = __builtin_amdgcn_mfma_f32_16x16x32_bf16(
                    af[mt], bfr[nt], acc[mt][nt], 0, 0, 0);
        __syncthreads();
    }
    #pragma unroll
    for (int mt = 0; mt < 4; ++mt) {
        #pragma unroll
        for (int r = 0; r < 4; ++r) {
            int row = mbase + wm + mt * 16 + quad * 4 + r;
            if (row >= M) continue;
            #pragma unroll
            for (int nt = 0; nt < 4; ++nt) {
                int col = nbase + wn + nt * 16 + l16;
                float v = acc[mt][nt][r];
                if (col < bias_n) v += bias[col];
                if (RELU) v = fmaxf(v, 0.f);
                C[(size_t)row * N + col] = f2bf(v);
            }
        }
    }
}

// ---------------- final: out = x + h4 @ W5 + b5 (one wave per node) ----------------

__global__ void final_kernel(const unsigned short* __restrict__ h4,
                             const float* __restrict__ W5, const float* __restrict__ b5,
                             const float* __restrict__ x, float* __restrict__ out) {
    int gt = blockIdx.x * blockDim.x + threadIdx.x;
    int node = gt >> 6;
    int lane = gt & 63;
    if (node >= NN) return;
    ushort4 hv = ((const ushort4*)(h4 + (size_t)node * 256))[lane];
    float hj[4] = {bf2f_raw(hv.x), bf2f_raw(hv.y), bf2f_raw(hv.z), bf2f_raw(hv.w)};
    float acc0 = 0.f, acc1 = 0.f, acc2 = 0.f;
    #pragma unroll
    for (int j = 0; j < 4; ++j) {
        int k = lane * 4 + j;
        acc0 += hj[j] * W5[k * 3 + 0];
        acc1 += hj[j] * W5[k * 3 + 1];
        acc2 += hj[j] * W5[k * 3 + 2];
    }
    #pragma unroll
    for (int off = 32; off; off >>= 1) {
        acc0 += __shfl_down(acc0, off);
        acc1 += __shfl_down(acc1, off);
        acc2 += __shfl_down(acc2, off);
    }
    if (lane == 0) {
        out[node * 3 + 0] = x[node * 3 + 0] + acc0 + b5[0];
        out[node * 3 + 1] = x[node * 3 + 1] + acc1 + b5[1];
        out[node * 3 + 2] = x[node * 3 + 2] + acc2 + b5[2];
    }
}

__global__ void fallback_copy_kernel(const float* __restrict__ x, float* __restrict__ out) {
    int t = blockIdx.x * blockDim.x + threadIdx.x;
    if (t < NN * 3) out[t] = x[t];
}

// ---------------- launcher ----------------

extern "C" void kernel_launch(void* const* d_in, const int* in_sizes, int n_in,
                              void* d_out, int out_size, void* d_ws, size_t ws_size,
                              hipStream_t stream) {
    const float* x  = (const float*)d_in[0];
    const int*   ei = (const int*)d_in[1];
    const float* W1 = (const float*)d_in[2];
    const float* b1 = (const float*)d_in[3];
    const float* W2 = (const float*)d_in[4];
    const float* b2 = (const float*)d_in[5];
    const float* W3 = (const float*)d_in[6];
    const float* b3 = (const float*)d_in[7];
    const float* W4 = (const float*)d_in[8];
    const float* b4 = (const float*)d_in[9];
    const float* W5 = (const float*)d_in[10];
    const float* b5 = (const float*)d_in[11];
    float* out = (float*)d_out;

    char* p = (char*)d_ws;
    auto alloc = [&](size_t bytes) -> void* {
        void* r = (void*)p;
        p += (bytes + 255) & ~(size_t)255;
        return r;
    };
    int* deg      = (int*)alloc((size_t)NN * 4);
    int* rowstart = (int*)alloc((size_t)(NN + 1) * 4);
    int* cursor   = (int*)alloc((size_t)NN * 4);
    int* csr      = (int*)alloc((size_t)NE * 4);
    unsigned short* Bt2 = (unsigned short*)alloc(256 * 64 * 2);    // [Wtb2^T ; Wb2^T]
    unsigned short* Bt3 = (unsigned short*)alloc(1024 * 128 * 2);  // [Wtb3^T ; Wb3^T]
    unsigned short* W4t = (unsigned short*)alloc(256 * 512 * 2);
    unsigned short* x1 = (unsigned short*)alloc((size_t)NN * 64 * 2);
    unsigned short* x2 = (unsigned short*)alloc((size_t)NN * 128 * 2);
    unsigned short* x3 = (unsigned short*)alloc((size_t)NN * 512 * 2);
    unsigned short* as_slab = (unsigned short*)alloc((size_t)NN * 1024 * 2);  // s1/as2/as3/h4
    size_t need = (size_t)(p - (char*)d_ws);
    if (ws_size < need) {
        fallback_copy_kernel<<<(NN * 3 + 255) / 256, 256, 0, stream>>>(x, out);
        return;
    }
    unsigned short* s1 = as_slab;
    unsigned short* h4 = as_slab;

    const int* src = ei;        // edge_index[0]
    const int* dst = ei + NE;   // edge_index[1]

    // CSR by dst (graph static across all 3 convs)
    hipMemsetAsync(deg, 0, (size_t)NN * 4, stream);
    hipMemsetAsync(cursor, 0, (size_t)NN * 4, stream);
    hist_kernel<<<(NE + 255) / 256, 256, 0, stream>>>(dst, deg);
    scan_kernel<<<1, 1024, 0, stream>>>(deg, rowstart);
    scatter_kernel<<<(NE + 255) / 256, 256, 0, stream>>>(src, dst, rowstart, cursor, csr);

    // bf16 transposed weights (combined [Wtb;Wb] for conv GEMMs)
    prep_split_t_kernel<64, 128><<<32, 256, 0, stream>>>(W2, Bt2, Bt2 + 128 * 64);
    prep_split_t_kernel<128, 512><<<256, 256, 0, stream>>>(W3, Bt3, Bt3 + 512 * 128);
    prep_t_kernel<512, 256><<<512, 256, 0, stream>>>(W4, W4t);

    // conv1: s1 = x@Wb1 ; x1 = relu(a1 + max_j s1[j])  (a1 inline)
    conv1_s_kernel<<<NN * 64 / 256, 256, 0, stream>>>(x, W1, s1);
    edge_fused_conv1_kernel<<<12500, 256, 0, stream>>>(s1, rowstart, csr, x, W1, b1, x1);

    // conv2: as2 = x1 @ [Wtb2|Wb2] (+b2 on a-half); x2 = relu(a2 + max s2)
    mfma_gemm_kernel<false><<<dim3(2, 391), 256, 0, stream>>>(
        x1, Bt2, b2, 128, as_slab, NN, 256, 64);
    edge_fused128_kernel<<<12500, 256, 0, stream>>>(as_slab, rowstart, csr, x2);

    // conv3: as3 = x2 @ [Wtb3|Wb3] (+b3 on a-half); x3 = relu(a3 + max s3)
    mfma_gemm_kernel<false><<<dim3(8, 391), 256, 0, stream>>>(
        x2, Bt3, b3, 512, as_slab, NN, 1024, 128);
    edge_fused512_kernel<<<12500, 256, 0, stream>>>(as_slab, rowstart, csr, x3);

    // h4 = relu(x3 @ W4 + b4)
    mfma_gemm_kernel<true><<<dim3(2, 391), 256, 0, stream>>>(
        x3, W4t, b4, 256, h4, NN, 256, 512);

    // out = x + h4 @ W5 + b5
    final_kernel<<<NN / 4, 256, 0, stream>>>(h4, W5, b5, x, out);
}